// Round 21
// baseline (169.427 us; speedup 1.0000x reference)
//
#include <hip/hip_runtime.h>
#include <hip/hip_bf16.h>
#include <stdint.h>
#include <stddef.h>

#define T_LEN   2048
#define C_IN_   512
#define D_MODEL_ 1024
#define B_SZ    32

typedef __hip_bfloat16 bf16;
typedef __attribute__((ext_vector_type(8))) short short8;
typedef __attribute__((ext_vector_type(4))) float f32x4;
typedef __attribute__((ext_vector_type(16))) float f32x16;

// ---------------------------------------------------------------------------
// async global->LDS, 16B per lane (linear dest: wave-uniform base + lane*16)
// ---------------------------------------------------------------------------
__device__ __forceinline__ void gload16(const void* g, void* l) {
    __builtin_amdgcn_global_load_lds(
        (const __attribute__((address_space(1))) uint32_t*)g,
        (__attribute__((address_space(3))) uint32_t*)l, 16, 0, 0);
}

// ---------------------------------------------------------------------------
// Kernel 1: bidirectional EWMA (R6 body) + fused W->bf16 (R19, frozen)
// ---------------------------------------------------------------------------
__global__ __launch_bounds__(512)
void ewma_kernel(const float* __restrict__ x, const float* __restrict__ W,
                 bf16* __restrict__ Wb, bf16* __restrict__ A) {
    const int tid  = threadIdx.x;
    const int wid  = tid >> 6;          // 0..7
    const int lane = tid & 63;
    const int half = lane >> 5;         // 0,1 -> which row of the wave
    const int j    = lane & 31;         // chunk (64 t's each)
    const int b    = blockIdx.x >> 5;   // 0..31
    const int cg   = blockIdx.x & 31;   // 0..31 (16 channels per block)
    const int c_local = (wid << 1) | half;       // 0..15

    const float AL = 0.1f, OM = 0.9f;
    const float Q  = 1.179018457773862e-3f;      // 0.9^64

    __shared__ float buf[8 * 2048];              // 64KB: 8 rows x 8KB
    __shared__ bf16  stg[32 * 16 * 16];          // 16KB output stage

    // ---- fused wconv: blocks 0..255 convert one float4 unit per thread
    if (blockIdx.x < 256) {
        int u = blockIdx.x * 512 + tid;          // 0..131071 (= all of W)
        float4 v = ((const float4*)W)[u];
        bf16* o = Wb + (size_t)u * 4;
        o[0] = __float2bfloat16(v.x);
        o[1] = __float2bfloat16(v.y);
        o[2] = __float2bfloat16(v.z);
        o[3] = __float2bfloat16(v.w);
    }

    float xr[64];
    const size_t xbase = ((size_t)b * C_IN_ + (cg << 4)) * T_LEN;
    const int srcu = tid ^ ((tid >> 4) & 7);     // involution on 16B units

    // ---- P1: two halves of 8 channel-rows through LDS
    #pragma unroll
    for (int h = 0; h < 2; ++h) {
        #pragma unroll
        for (int it = 0; it < 8; ++it)
            gload16(x + xbase + (size_t)(h * 8 + it) * T_LEN + srcu * 4,
                    (char*)buf + it * 8192 + tid * 16);
        asm volatile("s_waitcnt vmcnt(0)" ::: "memory");
        __syncthreads();
        if ((c_local >> 3) == h) {
            const char* rbase = (const char*)buf + (c_local & 7) * 8192;
            #pragma unroll
            for (int i = 0; i < 16; ++i) {
                int p = (j * 16 + i) ^ (j & 7);
                float4 v = *(const float4*)(rbase + p * 16);
                xr[4*i+0] = v.x; xr[4*i+1] = v.y;
                xr[4*i+2] = v.z; xr[4*i+3] = v.w;
            }
        }
        __syncthreads();                          // pulls drained before reuse
    }

    // ---- P2: local fwd scan
    float g = (j == 0) ? xr[0] : AL * xr[0];
    #pragma unroll
    for (int i = 1; i < 64; ++i) g = fmaf(OM, g, AL * xr[i]);

    // ---- P3: Kogge-Stone carry scan
    float F = g, coef = Q;
    #pragma unroll
    for (int d = 1; d < 32; d <<= 1) {
        float up = __shfl_up(F, d, 32);
        F += (j >= d) ? coef * up : 0.0f;
        coef *= coef;
    }
    float carry = __shfl_up(F, 1, 32);
    if (j == 0) carry = 0.0f;

    // ---- P4: seeded fwd recompute
    xr[0] = (j == 0) ? xr[0] : fmaf(OM, carry, AL * xr[0]);
    #pragma unroll
    for (int i = 1; i < 64; ++i) xr[i] = fmaf(OM, xr[i-1], AL * xr[i]);

    // ---- P5: local bwd scan from f
    float h2;
    {
        float incL = xr[63] - OM * xr[62];
        if (j == 31) incL *= 10.0f;
        h2 = incL;
        #pragma unroll
        for (int i = 62; i >= 1; --i) h2 = fmaf(OM, h2, xr[i] - OM * xr[i-1]);
        float inc0 = (j == 0) ? AL * xr[0] : (xr[0] - OM * carry);
        h2 = fmaf(OM, h2, inc0);
    }

    // ---- P6: bwd carry scan
    float Bv = h2; coef = Q;
    #pragma unroll
    for (int d = 1; d < 32; d <<= 1) {
        float dn = __shfl_down(Bv, d, 32);
        Bv += (j < 32 - d) ? coef * dn : 0.0f;
        coef *= coef;
    }
    float bnext = __shfl_down(Bv, 1, 32);
    if (j == 31) bnext = 0.0f;

    // ---- P7: final bwd recompute + combine
    {
        float bp = bnext;
        float incL = xr[63] - OM * xr[62];
        if (j == 31) incL *= 10.0f;
        float bb = fmaf(OM, bp, incL);
        xr[63] = 0.5f * (xr[63] + bb);
        bp = bb;
        #pragma unroll
        for (int i = 62; i >= 1; --i) {
            float inc = xr[i] - OM * xr[i-1];
            bb = fmaf(OM, bp, inc);
            xr[i] = 0.5f * (xr[i] + bb);
            bp = bb;
        }
        float inc0 = (j == 0) ? AL * xr[0] : (xr[0] - OM * carry);
        bb = fmaf(OM, bp, inc0);
        xr[0] = 0.5f * (xr[0] + bb);
    }

    // ---- P8: LDS transpose stage -> coalesced bf16 writes
    const size_t outbase = (size_t)(b * T_LEN) * C_IN_ + (cg << 4);
    #pragma unroll
    for (int grp = 0; grp < 4; ++grp) {
        __syncthreads();
        #pragma unroll
        for (int ii = 0; ii < 16; ++ii) {
            int elem = ((j * 16 + ii) * 16 + c_local) ^ ((j & 7) << 3);
            stg[elem] = __float2bfloat16(xr[grp * 16 + ii]);
        }
        __syncthreads();
        #pragma unroll
        for (int r = 0; r < 2; ++r) {
            int u   = tid * 2 + r;               // 1024 16B-units
            int jj  = u >> 5;
            int ii  = (u >> 1) & 15;
            int hf  = u & 1;
            int elem = ((jj * 16 + ii) * 16 + hf * 8) ^ ((jj & 7) << 3);
            float4 v = *(const float4*)&stg[elem];
            int t = jj * 64 + grp * 16 + ii;
            *(float4*)(A + outbase + (size_t)t * C_IN_ + hf * 8) = v;
        }
    }
}

// ---------------------------------------------------------------------------
// Kernel 2: GEMM  out[m][n] = sum_k A[m][k]*W[n][k] + bias[n]
// R21: R20's structure (4-set, 3-kt lookahead, vmcnt(8), no lgkm pin) with
// the MFMA shape swapped 16x16x32 -> 32x32x16: wave-tile 64x64 = 2x2 of
// 32x32 tiles; per kt 8 MFMAs (~64cyc) instead of 16 (~80cyc), same 8
// ds_read_b128. A/B operand layout: row=lane&31, k=(lane>>5)*8+e (analog
// of the verified 16x16x32 mapping); C/D: col=lane&31,
// row=(r&3)+8*(r>>2)+4*(lane>>5) [guide m74/m101].
// ---------------------------------------------------------------------------
#define MFMA32(a, b, c) __builtin_amdgcn_mfma_f32_32x32x16_bf16(a, b, c, 0, 0, 0)

__global__ __launch_bounds__(256, 2)
void gemm_kernel(const bf16* __restrict__ Amat, const bf16* __restrict__ Wb,
                 const float* __restrict__ bias, float* __restrict__ out) {
    constexpr int K = C_IN_, N = D_MODEL_;
    extern __shared__ bf16 lds[];                // 4 sets x (A 8KB + B 8KB)
    const int tid  = threadIdx.x;
    const int wid  = tid >> 6, lane = tid & 63;
    const int wr   = wid >> 1, wc = wid & 1;     // 2x2 wave grid, wave 64x64
    const int l31  = lane & 31;
    const int l5   = lane >> 5;                  // k-half selector

    // T1: bijective XCD swizzle (4096 blocks); 8 nb share each A panel
    int bid = blockIdx.x;
    int swz = (bid & 7) * 512 + (bid >> 3);
    const int mb = swz >> 3, nb = swz & 7;       // 512 x 8
    const int m0 = mb * 128, n0 = nb * 128;

    // set s at byte s*16384: A 8KB then B 8KB
    auto stage = [&](int kt) {
        const int s = kt & 3;
        char* la = (char*)lds + s * 16384;
        char* lb = la + 8192;
        #pragma unroll
        for (int r = 0; r < 2; ++r) {
            int q = tid + r * 256;
            int row = q >> 2, u = q & 3;
            gload16(Amat + (size_t)(m0 + row) * K + kt * 32 + ((u ^ ((row >> 1) & 3)) << 3),
                    la + q * 16);
        }
        #pragma unroll
        for (int r = 0; r < 2; ++r) {
            int q = tid + r * 256;
            int row = q >> 2, u = q & 3;
            gload16(Wb + (size_t)(n0 + row) * K + kt * 32 + ((u ^ ((row >> 1) & 3)) << 3),
                    lb + q * 16);
        }
    };
    // 32x32x16 A-frag: row = wr*64 + mt*32 + l31, unit u = ks*2 + l5
    auto rdA = [&](int s, int mt, int ks) -> short8 {
        int row = wr * 64 + mt * 32 + l31;
        int u   = ks * 2 + l5;
        return *(const short8*)((const char*)lds + s * 16384
                                + row * 64 + ((u ^ ((row >> 1) & 3)) << 4));
    };
    auto rdB = [&](int s, int nt, int ks) -> short8 {
        int row = wc * 64 + nt * 32 + l31;
        int u   = ks * 2 + l5;
        return *(const short8*)((const char*)lds + s * 16384 + 8192
                                + row * 64 + ((u ^ ((row >> 1) & 3)) << 4));
    };

    f32x16 acc[2][2];
    #pragma unroll
    for (int mt = 0; mt < 2; ++mt)
        #pragma unroll
        for (int nt = 0; nt < 2; ++nt)
            #pragma unroll
            for (int r = 0; r < 16; ++r) acc[mt][nt][r] = 0.f;

    // ---- prologue: stage kt 0,1,2 (12 loads); wait kt0 (leave 8)
    stage(0);
    stage(1);
    stage(2);
    asm volatile("s_waitcnt vmcnt(8)" ::: "memory");
    __builtin_amdgcn_s_barrier();

    // ---- K loop: 16 K-tiles of 32; 3-kt lookahead, vmcnt(8) checkpoints.
    // No lgkm pin: compiler inserts fine-grained counted waits.
    #pragma unroll
    for (int kt = 0; kt < 16; ++kt) {
        const int s = kt & 3;
        short8 a[2][2], b[2][2];
        #pragma unroll
        for (int mt = 0; mt < 2; ++mt)
            #pragma unroll
            for (int ks = 0; ks < 2; ++ks) a[mt][ks] = rdA(s, mt, ks);
        #pragma unroll
        for (int nt = 0; nt < 2; ++nt)
            #pragma unroll
            for (int ks = 0; ks < 2; ++ks) b[nt][ks] = rdB(s, nt, ks);

        if (kt < 13) stage(kt + 3);              // set (kt+3)&3: read done @kt-1

        __builtin_amdgcn_s_setprio(1);
        #pragma unroll
        for (int mt = 0; mt < 2; ++mt)
            #pragma unroll
            for (int nt = 0; nt < 2; ++nt) {
                acc[mt][nt] = MFMA32(a[mt][0], b[nt][0], acc[mt][nt]);
                acc[mt][nt] = MFMA32(a[mt][1], b[nt][1], acc[mt][nt]);
            }
        __builtin_amdgcn_s_setprio(0);

        // ensure stage(kt+1) landed before next iter reads it
        if (kt < 13)       asm volatile("s_waitcnt vmcnt(8)" ::: "memory");
        else if (kt == 13) asm volatile("s_waitcnt vmcnt(4)" ::: "memory");
        else if (kt == 14) asm volatile("s_waitcnt vmcnt(0)" ::: "memory");
        __builtin_amdgcn_s_barrier();
    }

    // ---- epilogue: C write + bias (fp32); 32x32 C/D layout
    #pragma unroll
    for (int mt = 0; mt < 2; ++mt) {
        #pragma unroll
        for (int nt = 0; nt < 2; ++nt) {
            int col = n0 + wc * 64 + nt * 32 + l31;
            float bv = bias[col];
            int mrow = m0 + wr * 64 + mt * 32 + 4 * l5;
            #pragma unroll
            for (int r = 0; r < 16; ++r) {
                int row = mrow + (r & 3) + 8 * (r >> 2);
                out[(size_t)row * N + col] = acc[mt][nt][r] + bv;
            }
        }
    }
}

// ---------------------------------------------------------------------------
extern "C" void kernel_launch(void* const* d_in, const int* in_sizes, int n_in,
                              void* d_out, int out_size, void* d_ws, size_t ws_size,
                              hipStream_t stream) {
    const float* x    = (const float*)d_in[0];
    const float* W    = (const float*)d_in[1];
    const float* bias = (const float*)d_in[2];
    float* out = (float*)d_out;

    bf16* Wb   = (bf16*)d_ws;                          // 1MB
    bf16* Amat = (bf16*)((char*)d_ws + (1 << 21));     // 64MB at +2MB

    hipLaunchKernelGGL(ewma_kernel, dim3(B_SZ * 32), dim3(512), 0, stream,
                       x, W, Wb, Amat);
    hipLaunchKernelGGL(gemm_kernel,
                       dim3((B_SZ * T_LEN / 128) * (D_MODEL_ / 128)),
                       dim3(256), 65536, stream, Amat, Wb, bias, out);
}

// Round 22
// 168.056 us; speedup vs baseline: 1.0082x; 1.0082x over previous
//
#include <hip/hip_runtime.h>
#include <hip/hip_bf16.h>
#include <stdint.h>
#include <stddef.h>

#define T_LEN   2048
#define C_IN_   512
#define D_MODEL_ 1024
#define B_SZ    32

typedef __hip_bfloat16 bf16;
typedef __attribute__((ext_vector_type(8))) short short8;
typedef __attribute__((ext_vector_type(4))) float f32x4;

// ---------------------------------------------------------------------------
// async global->LDS, 16B per lane (linear dest: wave-uniform base + lane*16)
// ---------------------------------------------------------------------------
__device__ __forceinline__ void gload16(const void* g, void* l) {
    __builtin_amdgcn_global_load_lds(
        (const __attribute__((address_space(1))) uint32_t*)g,
        (__attribute__((address_space(3))) uint32_t*)l, 16, 0, 0);
}

// ---------------------------------------------------------------------------
// Kernel 1: bidirectional EWMA (R6 body) + fused W->bf16 (R19, frozen)
// ---------------------------------------------------------------------------
__global__ __launch_bounds__(512)
void ewma_kernel(const float* __restrict__ x, const float* __restrict__ W,
                 bf16* __restrict__ Wb, bf16* __restrict__ A) {
    const int tid  = threadIdx.x;
    const int wid  = tid >> 6;          // 0..7
    const int lane = tid & 63;
    const int half = lane >> 5;         // 0,1 -> which row of the wave
    const int j    = lane & 31;         // chunk (64 t's each)
    const int b    = blockIdx.x >> 5;   // 0..31
    const int cg   = blockIdx.x & 31;   // 0..31 (16 channels per block)
    const int c_local = (wid << 1) | half;       // 0..15

    const float AL = 0.1f, OM = 0.9f;
    const float Q  = 1.179018457773862e-3f;      // 0.9^64

    __shared__ float buf[8 * 2048];              // 64KB: 8 rows x 8KB
    __shared__ bf16  stg[32 * 16 * 16];          // 16KB output stage

    // ---- fused wconv: blocks 0..255 convert one float4 unit per thread
    if (blockIdx.x < 256) {
        int u = blockIdx.x * 512 + tid;          // 0..131071 (= all of W)
        float4 v = ((const float4*)W)[u];
        bf16* o = Wb + (size_t)u * 4;
        o[0] = __float2bfloat16(v.x);
        o[1] = __float2bfloat16(v.y);
        o[2] = __float2bfloat16(v.z);
        o[3] = __float2bfloat16(v.w);
    }

    float xr[64];
    const size_t xbase = ((size_t)b * C_IN_ + (cg << 4)) * T_LEN;
    const int srcu = tid ^ ((tid >> 4) & 7);     // involution on 16B units

    // ---- P1: two halves of 8 channel-rows through LDS
    #pragma unroll
    for (int h = 0; h < 2; ++h) {
        #pragma unroll
        for (int it = 0; it < 8; ++it)
            gload16(x + xbase + (size_t)(h * 8 + it) * T_LEN + srcu * 4,
                    (char*)buf + it * 8192 + tid * 16);
        asm volatile("s_waitcnt vmcnt(0)" ::: "memory");
        __syncthreads();
        if ((c_local >> 3) == h) {
            const char* rbase = (const char*)buf + (c_local & 7) * 8192;
            #pragma unroll
            for (int i = 0; i < 16; ++i) {
                int p = (j * 16 + i) ^ (j & 7);
                float4 v = *(const float4*)(rbase + p * 16);
                xr[4*i+0] = v.x; xr[4*i+1] = v.y;
                xr[4*i+2] = v.z; xr[4*i+3] = v.w;
            }
        }
        __syncthreads();                          // pulls drained before reuse
    }

    // ---- P2: local fwd scan
    float g = (j == 0) ? xr[0] : AL * xr[0];
    #pragma unroll
    for (int i = 1; i < 64; ++i) g = fmaf(OM, g, AL * xr[i]);

    // ---- P3: Kogge-Stone carry scan
    float F = g, coef = Q;
    #pragma unroll
    for (int d = 1; d < 32; d <<= 1) {
        float up = __shfl_up(F, d, 32);
        F += (j >= d) ? coef * up : 0.0f;
        coef *= coef;
    }
    float carry = __shfl_up(F, 1, 32);
    if (j == 0) carry = 0.0f;

    // ---- P4: seeded fwd recompute
    xr[0] = (j == 0) ? xr[0] : fmaf(OM, carry, AL * xr[0]);
    #pragma unroll
    for (int i = 1; i < 64; ++i) xr[i] = fmaf(OM, xr[i-1], AL * xr[i]);

    // ---- P5: local bwd scan from f
    float h2;
    {
        float incL = xr[63] - OM * xr[62];
        if (j == 31) incL *= 10.0f;
        h2 = incL;
        #pragma unroll
        for (int i = 62; i >= 1; --i) h2 = fmaf(OM, h2, xr[i] - OM * xr[i-1]);
        float inc0 = (j == 0) ? AL * xr[0] : (xr[0] - OM * carry);
        h2 = fmaf(OM, h2, inc0);
    }

    // ---- P6: bwd carry scan
    float Bv = h2; coef = Q;
    #pragma unroll
    for (int d = 1; d < 32; d <<= 1) {
        float dn = __shfl_down(Bv, d, 32);
        Bv += (j < 32 - d) ? coef * dn : 0.0f;
        coef *= coef;
    }
    float bnext = __shfl_down(Bv, 1, 32);
    if (j == 31) bnext = 0.0f;

    // ---- P7: final bwd recompute + combine
    {
        float bp = bnext;
        float incL = xr[63] - OM * xr[62];
        if (j == 31) incL *= 10.0f;
        float bb = fmaf(OM, bp, incL);
        xr[63] = 0.5f * (xr[63] + bb);
        bp = bb;
        #pragma unroll
        for (int i = 62; i >= 1; --i) {
            float inc = xr[i] - OM * xr[i-1];
            bb = fmaf(OM, bp, inc);
            xr[i] = 0.5f * (xr[i] + bb);
            bp = bb;
        }
        float inc0 = (j == 0) ? AL * xr[0] : (xr[0] - OM * carry);
        bb = fmaf(OM, bp, inc0);
        xr[0] = 0.5f * (xr[0] + bb);
    }

    // ---- P8: LDS transpose stage -> coalesced bf16 writes
    const size_t outbase = (size_t)(b * T_LEN) * C_IN_ + (cg << 4);
    #pragma unroll
    for (int grp = 0; grp < 4; ++grp) {
        __syncthreads();
        #pragma unroll
        for (int ii = 0; ii < 16; ++ii) {
            int elem = ((j * 16 + ii) * 16 + c_local) ^ ((j & 7) << 3);
            stg[elem] = __float2bfloat16(xr[grp * 16 + ii]);
        }
        __syncthreads();
        #pragma unroll
        for (int r = 0; r < 2; ++r) {
            int u   = tid * 2 + r;               // 1024 16B-units
            int jj  = u >> 5;
            int ii  = (u >> 1) & 15;
            int hf  = u & 1;
            int elem = ((jj * 16 + ii) * 16 + hf * 8) ^ ((jj & 7) << 3);
            float4 v = *(const float4*)&stg[elem];
            int t = jj * 64 + grp * 16 + ii;
            *(float4*)(A + outbase + (size_t)t * C_IN_ + hf * 8) = v;
        }
    }
}

// ---------------------------------------------------------------------------
// Kernel 2: GEMM  out[m][n] = sum_k A[m][k]*W[n][k] + bias[n]
// (byte-identical to R20 — best measured total: 4-set, 3-kt lookahead,
// vmcnt(8) checkpoints, NO lgkm pin, 16x16x32 MFMA. R21's 32x32x16 shape
// experiment regressed 4.7us and is reverted.)
// ---------------------------------------------------------------------------
#define MFMA(a, b, c) __builtin_amdgcn_mfma_f32_16x16x32_bf16(a, b, c, 0, 0, 0)

__global__ __launch_bounds__(256, 2)
void gemm_kernel(const bf16* __restrict__ Amat, const bf16* __restrict__ Wb,
                 const float* __restrict__ bias, float* __restrict__ out) {
    constexpr int K = C_IN_, N = D_MODEL_;
    extern __shared__ bf16 lds[];                // 4 sets x (A 8KB + B 8KB)
    const int tid  = threadIdx.x;
    const int wid  = tid >> 6, lane = tid & 63;
    const int wr   = wid >> 1, wc = wid & 1;     // 2x2 wave grid, wave 64x64
    const int lr   = lane & 15;
    const int lg   = lane >> 4;

    // T1: bijective XCD swizzle (4096 blocks); 8 nb share each A panel
    int bid = blockIdx.x;
    int swz = (bid & 7) * 512 + (bid >> 3);
    const int mb = swz >> 3, nb = swz & 7;       // 512 x 8
    const int m0 = mb * 128, n0 = nb * 128;

    // set s at byte s*16384: A 8KB then B 8KB
    auto stage = [&](int kt) {
        const int s = kt & 3;
        char* la = (char*)lds + s * 16384;
        char* lb = la + 8192;
        #pragma unroll
        for (int r = 0; r < 2; ++r) {
            int q = tid + r * 256;
            int row = q >> 2, u = q & 3;
            gload16(Amat + (size_t)(m0 + row) * K + kt * 32 + ((u ^ ((row >> 1) & 3)) << 3),
                    la + q * 16);
        }
        #pragma unroll
        for (int r = 0; r < 2; ++r) {
            int q = tid + r * 256;
            int row = q >> 2, u = q & 3;
            gload16(Wb + (size_t)(n0 + row) * K + kt * 32 + ((u ^ ((row >> 1) & 3)) << 3),
                    lb + q * 16);
        }
    };
    auto rdA = [&](int s, int f) -> short8 {
        int row = wr * 64 + f * 16 + lr;
        return *(const short8*)((const char*)lds + s * 16384
                                + row * 64 + ((lg ^ ((row >> 1) & 3)) << 4));
    };
    auto rdB = [&](int s, int n) -> short8 {
        int row = wc * 64 + n * 16 + lr;
        return *(const short8*)((const char*)lds + s * 16384 + 8192
                                + row * 64 + ((lg ^ ((row >> 1) & 3)) << 4));
    };

    f32x4 acc[4][4];
    #pragma unroll
    for (int f = 0; f < 4; ++f)
        #pragma unroll
        for (int n = 0; n < 4; ++n) acc[f][n] = (f32x4){0.f, 0.f, 0.f, 0.f};

    // ---- prologue: stage kt 0,1,2 (12 loads); wait kt0 (leave 8)
    stage(0);
    stage(1);
    stage(2);
    asm volatile("s_waitcnt vmcnt(8)" ::: "memory");
    __builtin_amdgcn_s_barrier();

    // ---- K loop: 16 K-tiles of 32; 3-kt lookahead, vmcnt(8) checkpoints.
    // NO lgkmcnt / sched_barrier between reads and MFMA — compiler inserts
    // fine-grained counted waits per dependency.
    #pragma unroll
    for (int kt = 0; kt < 16; ++kt) {
        const int s = kt & 3;
        short8 a[4], b[4];
        #pragma unroll
        for (int f = 0; f < 4; ++f) a[f] = rdA(s, f);
        #pragma unroll
        for (int n = 0; n < 4; ++n) b[n] = rdB(s, n);

        if (kt < 13) stage(kt + 3);              // set (kt+3)&3: read done @kt-1

        __builtin_amdgcn_s_setprio(1);
        #pragma unroll
        for (int f = 0; f < 4; ++f)
            #pragma unroll
            for (int n = 0; n < 4; ++n)
                acc[f][n] = MFMA(a[f], b[n], acc[f][n]);
        __builtin_amdgcn_s_setprio(0);

        // ensure stage(kt+1) landed before next iter reads it
        if (kt < 13)       asm volatile("s_waitcnt vmcnt(8)" ::: "memory");
        else if (kt == 13) asm volatile("s_waitcnt vmcnt(4)" ::: "memory");
        else if (kt == 14) asm volatile("s_waitcnt vmcnt(0)" ::: "memory");
        __builtin_amdgcn_s_barrier();
    }

    // ---- epilogue: C write + bias (fp32)
    const int crow = lg << 2;
    #pragma unroll
    for (int n = 0; n < 4; ++n) {
        int col = n0 + wc * 64 + n * 16 + lr;
        float bv = bias[col];
        #pragma unroll
        for (int f = 0; f < 4; ++f) {
            size_t rbase = (size_t)(m0 + wr * 64 + f * 16 + crow) * N + col;
            #pragma unroll
            for (int r = 0; r < 4; ++r)
                out[rbase + (size_t)r * N] = acc[f][n][r] + bv;
        }
    }
}

// ---------------------------------------------------------------------------
extern "C" void kernel_launch(void* const* d_in, const int* in_sizes, int n_in,
                              void* d_out, int out_size, void* d_ws, size_t ws_size,
                              hipStream_t stream) {
    const float* x    = (const float*)d_in[0];
    const float* W    = (const float*)d_in[1];
    const float* bias = (const float*)d_in[2];
    float* out = (float*)d_out;

    bf16* Wb   = (bf16*)d_ws;                          // 1MB
    bf16* Amat = (bf16*)((char*)d_ws + (1 << 21));     // 64MB at +2MB

    hipLaunchKernelGGL(ewma_kernel, dim3(B_SZ * 32), dim3(512), 0, stream,
                       x, W, Wb, Amat);
    hipLaunchKernelGGL(gemm_kernel,
                       dim3((B_SZ * T_LEN / 128) * (D_MODEL_ / 128)),
                       dim3(256), 65536, stream, Amat, Wb, bias, out);
}